// Round 9
// baseline (13679.535 us; speedup 1.0000x reference)
//
#include <hip/hip_runtime.h>
#include <hip/hip_cooperative_groups.h>

namespace cg = cooperative_groups;

constexpr int N    = 4096;
constexpr int T    = 2048;
constexpr int NBLK = 256;                 // one WG per CU
constexpr int NTHR = 1024;                // 16 waves
constexpr int ROWS_PER_WG = 16;

struct Params {
    const float *x_in, *w, *E_L, *C_m, *G, *R_I, *f_v, *f_I, *dts, *b_s,
                *a_v, *b_v, *tinf, *dV, *I_A, *v0, *ts0, *tv0, *ia0;
    float *out;          // [2, T, N]
    unsigned *flags;     // 256 packed u32 flags (1 KB) at d_ws
    float *ia_buf;       // double buffer 2*N floats at d_ws + 4 KB
};

#define DOT(wv, iv) ((wv).x*(iv).x + (wv).y*(iv).y + (wv).z*(iv).z + (wv).w*(iv).w)
#define AGLD(ptr) __hip_atomic_load(ptr, __ATOMIC_RELAXED, __HIP_MEMORY_SCOPE_AGENT)
#define AGST(ptr, val) __hip_atomic_store(ptr, val, __ATOMIC_RELAXED, __HIP_MEMORY_SCOPE_AGENT)

__global__ __launch_bounds__(NTHR, 1)
void glif_persistent(Params p)
{
    cg::grid_group grid = cg::this_grid();
    __shared__ float part[16 * 16];       // [row][wave], 1 KB

    const int tid  = threadIdx.x;         // == wave*64 + lane == float4 column
    const int wg   = blockIdx.x;
    const int wave = tid >> 6;
    const int lane = tid & 63;

    // state-owner mapping (wave 0, lanes 0..15). Clamped for other lanes so
    // every memory access below is in-bounds; extra lanes compute unused dups.
    const int lrow = (lane < 15) ? lane : 15;        // 0..15
    const int srow = wg * ROWS_PER_WG + lrow;        // in [0, N)

    // ---- per-row params/state (used only by wave 0, lanes < 16)
    const float c_EL = p.E_L[srow],  c_Cm = p.C_m[srow], c_G   = p.G[srow];
    const float c_RI = p.R_I[srow],  c_fv = p.f_v[srow], c_fI  = p.f_I[srow];
    const float c_dts = p.dts[srow], c_bs = p.b_s[srow], c_av  = p.a_v[srow];
    const float c_bv  = p.b_v[srow], c_tinf = p.tinf[srow];
    const float c_dV  = p.dV[srow],  c_IA = p.I_A[srow];
    float v  = p.v0[srow], ts = p.ts0[srow], tv = p.tv0[srow];
    float ia_self = p.ia0[srow];

    // ---- w: 16 rows x this thread's float4 column slice (64 VGPR/AGPR)
    const float4* w4 = (const float4*)p.w;           // [4096][1024] float4
    const size_t rb  = (size_t)wg * ROWS_PER_WG * (N / 4) + tid;
    const float4 w0  = w4[rb +  0 * (N/4)], w1  = w4[rb +  1 * (N/4)],
                 w2  = w4[rb +  2 * (N/4)], w3  = w4[rb +  3 * (N/4)],
                 w4r = w4[rb +  4 * (N/4)], w5  = w4[rb +  5 * (N/4)],
                 w6  = w4[rb +  6 * (N/4)], w7  = w4[rb +  7 * (N/4)],
                 w8  = w4[rb +  8 * (N/4)], w9  = w4[rb +  9 * (N/4)],
                 w10 = w4[rb + 10 * (N/4)], w11 = w4[rb + 11 * (N/4)],
                 w12 = w4[rb + 12 * (N/4)], w13 = w4[rb + 13 * (N/4)],
                 w14 = w4[rb + 14 * (N/4)], w15 = w4[rb + 15 * (N/4)];

    // ---- init: zero own flag (kills 0xAA poison + stale replay tags)
    if (tid == 0) AGST(&p.flags[wg], 0u);
    // initial I_add float4 for this thread's columns, straight from input
    float4 iav = ((const float4*)p.ia0)[tid];
    grid.sync();                          // once per launch

    float x = p.x_in[srow];               // x for t=0 (wave0/lane<16 meaningful)

    for (int t = 0; t < T; ++t) {
        // ---- 16 partial dots over this thread's 4 columns (pure registers)
        float p0  = DOT(w0 , iav), p1  = DOT(w1 , iav),
              p2  = DOT(w2 , iav), p3  = DOT(w3 , iav),
              p4  = DOT(w4r, iav), p5  = DOT(w5 , iav),
              p6  = DOT(w6 , iav), p7  = DOT(w7 , iav),
              p8  = DOT(w8 , iav), p9  = DOT(w9 , iav),
              p10 = DOT(w10, iav), p11 = DOT(w11, iav),
              p12 = DOT(w12, iav), p13 = DOT(w13, iav),
              p14 = DOT(w14, iav), p15 = DOT(w15, iav);

        // ---- butterfly: every lane ends with the wave's 16 column-slice sums
        #define BFLY(m) \
            p0  += __shfl_xor(p0 , m, 64); p1  += __shfl_xor(p1 , m, 64); \
            p2  += __shfl_xor(p2 , m, 64); p3  += __shfl_xor(p3 , m, 64); \
            p4  += __shfl_xor(p4 , m, 64); p5  += __shfl_xor(p5 , m, 64); \
            p6  += __shfl_xor(p6 , m, 64); p7  += __shfl_xor(p7 , m, 64); \
            p8  += __shfl_xor(p8 , m, 64); p9  += __shfl_xor(p9 , m, 64); \
            p10 += __shfl_xor(p10, m, 64); p11 += __shfl_xor(p11, m, 64); \
            p12 += __shfl_xor(p12, m, 64); p13 += __shfl_xor(p13, m, 64); \
            p14 += __shfl_xor(p14, m, 64); p15 += __shfl_xor(p15, m, 64);
        BFLY(32) BFLY(16) BFLY(8) BFLY(4) BFLY(2) BFLY(1)
        #undef BFLY

        // ---- lane 0 of each wave deposits 16 partials: part[row][wave]
        if (lane == 0) {
            part[ 0*16 + wave] = p0;  part[ 1*16 + wave] = p1;
            part[ 2*16 + wave] = p2;  part[ 3*16 + wave] = p3;
            part[ 4*16 + wave] = p4;  part[ 5*16 + wave] = p5;
            part[ 6*16 + wave] = p6;  part[ 7*16 + wave] = p7;
            part[ 8*16 + wave] = p8;  part[ 9*16 + wave] = p9;
            part[10*16 + wave] = p10; part[11*16 + wave] = p11;
            part[12*16 + wave] = p12; part[13*16 + wave] = p13;
            part[14*16 + wave] = p14; part[15*16 + wave] = p15;
        }
        __syncthreads();                  // A: partials visible to wave 0

        const bool notlast = (t + 1 < T);
        float* dst = p.ia_buf + (size_t)((t + 1) & 1) * N;

        if (wave == 0) {
            // ---- final reduce: lane rr sums its row over 16 waves
            const int rr = lane & 15;     // lanes 16..63 duplicate, unused
            float4 r0 = *(const float4*)&part[rr * 16 +  0];
            float4 r1 = *(const float4*)&part[rr * 16 +  4];
            float4 r2 = *(const float4*)&part[rr * 16 +  8];
            float4 r3 = *(const float4*)&part[rr * 16 + 12];
            float a = (r0.x + r0.y + r0.z + r0.w) + (r1.x + r1.y + r1.z + r1.w)
                    + (r2.x + r2.y + r2.z + r2.w) + (r3.x + r3.y + r3.z + r3.w);

            // ---- neuron update (lanes >= 16 compute harmless duplicates)
            float I      = x + a;
            float dv     = (I * c_RI - c_G * (v - c_EL)) / c_Cm;
            float v_next = v + dv;
            float thr    = ts + tv;
            float ssoft  = 1.f / (1.f + __expf(thr - v_next));
            float ia_new = (1.f - c_fI) * ia_self + ssoft * c_IA;

            // ---- publish: ONE coalesced 64 B store for the WG's 16 values
            if (lane < 16) AGST(&dst[srow], ia_new);
            asm volatile("s_waitcnt vmcnt(0)" ::: "memory");
            if (lane == 0 && notlast)
                AGST(&p.flags[wg], (unsigned)(t + 1));

            // ---- bookkeeping + out stores + x prefetch in the poll shadow
            bool  sp      = (v_next >= thr);
            float v_reset = c_EL + c_fv * (v - c_EL) - c_dV;
            float v_new   = sp ? v_reset : v_next;
            float ts_new  = (1.f - c_bs) * ts + (sp ? c_dts : 0.f);
            float dtv     = c_av * (v_new - c_EL) - c_bv * (tv - c_tinf);
            float tv_new  = tv + (sp ? 0.f : dtv);
            v = v_new; ts = ts_new; tv = tv_new; ia_self = ia_new;
            if (lane < 16) {
                p.out[(size_t)t * N + srow] = v_new;
                p.out[(size_t)T * N + (size_t)t * N + srow] = ssoft;
                if (notlast) x = p.x_in[(size_t)(t + 1) * N + srow];
            }

            // ---- poll all 256 flags (1 KB): 2 u64/lane, sticky >=
            if (notlast) {
                const unsigned tgt = (unsigned)(t + 1);
                const unsigned long long* f64 =
                    (const unsigned long long*)p.flags;
                bool d0 = false, d1 = false;
                for (;;) {
                    if (!d0) {
                        unsigned long long q = AGLD(&f64[lane]);
                        d0 = ((unsigned)q >= tgt) & ((unsigned)(q >> 32) >= tgt);
                    }
                    if (!d1) {
                        unsigned long long q = AGLD(&f64[lane + 64]);
                        d1 = ((unsigned)q >= tgt) & ((unsigned)(q >> 32) >= tgt);
                    }
                    if (__all(d0 && d1)) break;
                    __builtin_amdgcn_s_sleep(1);
                }
            }
        }
        __syncthreads();                  // B: all 256 WGs have published

        if (notlast) {
            // ---- every thread reads ITS OWN float4 of fresh I_add (L3-direct)
            const unsigned long long* s64 = (const unsigned long long*)dst;
            unsigned long long qa = AGLD(&s64[2 * tid + 0]);
            unsigned long long qb = AGLD(&s64[2 * tid + 1]);
            iav.x = __uint_as_float((unsigned)qa);
            iav.y = __uint_as_float((unsigned)(qa >> 32));
            iav.z = __uint_as_float((unsigned)qb);
            iav.w = __uint_as_float((unsigned)(qb >> 32));
        }
    }
}

extern "C" void kernel_launch(void* const* d_in, const int* in_sizes, int n_in,
                              void* d_out, int out_size, void* d_ws, size_t ws_size,
                              hipStream_t stream)
{
    Params p;
    p.x_in = (const float*)d_in[0];
    p.w    = (const float*)d_in[1];
    p.E_L  = (const float*)d_in[2];
    p.C_m  = (const float*)d_in[3];
    p.G    = (const float*)d_in[4];
    p.R_I  = (const float*)d_in[5];
    p.f_v  = (const float*)d_in[6];
    p.f_I  = (const float*)d_in[7];
    p.dts  = (const float*)d_in[8];
    p.b_s  = (const float*)d_in[9];
    p.a_v  = (const float*)d_in[10];
    p.b_v  = (const float*)d_in[11];
    p.tinf = (const float*)d_in[12];
    p.dV   = (const float*)d_in[13];
    p.I_A  = (const float*)d_in[14];
    p.v0   = (const float*)d_in[15];
    p.ts0  = (const float*)d_in[16];
    p.tv0  = (const float*)d_in[17];
    p.ia0  = (const float*)d_in[18];
    p.out  = (float*)d_out;
    p.flags  = (unsigned*)d_ws;                      // 256 * 4 B = 1 KB
    p.ia_buf = (float*)((char*)d_ws + 4096);         // 2*N*4 = 32 KB

    void* args[] = { &p };
    hipLaunchCooperativeKernel((const void*)glif_persistent,
                               dim3(NBLK), dim3(NTHR), args, 0, stream);
}

// Round 10
// 10960.126 us; speedup vs baseline: 1.2481x; 1.2481x over previous
//
#include <hip/hip_runtime.h>
#include <hip/hip_cooperative_groups.h>

namespace cg = cooperative_groups;

constexpr int N    = 4096;
constexpr int T    = 2048;
constexpr int NBLK = 256;                 // one WG per CU
constexpr int NTHR = 1024;                // 16 waves
constexpr int ROWS_PER_WG = 16;

struct Params {
    const float *x_in, *w, *E_L, *C_m, *G, *R_I, *f_v, *f_I, *dts, *b_s,
                *a_v, *b_v, *tinf, *dV, *I_A, *v0, *ts0, *tv0, *ia0;
    float *out;          // [2, T, N]
    unsigned *flags;     // 256 u32 flags (1 KB) at d_ws
    float *ia_buf;       // double buffer 2*N floats at d_ws + 4 KB
};

#define DOT(wv, iv) ((wv).x*(iv).x + (wv).y*(iv).y + (wv).z*(iv).z + (wv).w*(iv).w)
#define AGLD(ptr) __hip_atomic_load(ptr, __ATOMIC_RELAXED, __HIP_MEMORY_SCOPE_AGENT)
#define AGST(ptr, val) __hip_atomic_store(ptr, val, __ATOMIC_RELAXED, __HIP_MEMORY_SCOPE_AGENT)

__global__ __launch_bounds__(NTHR, 1)
void glif_persistent(Params p)
{
    cg::grid_group grid = cg::this_grid();
    __shared__ float ia_lds[2][N];        // 32 KB double buffer
    __shared__ float part[32];            // [row*2 + slice]

    const int tid  = threadIdx.x;
    const int wg   = blockIdx.x;
    const int wave = tid >> 6;
    const int lane = tid & 63;
    const int g    = wave >> 1;           // row-pair group 0..7
    const int c    = wave & 1;            // column half 0..1
    const int rowA = wg * ROWS_PER_WG + 2 * g;   // this wave: rows rowA, rowA+1

    // wave-0 neuron ownership: lane r < 16 owns row wg*16 + r. Other lanes
    // clamp to row 15 (in-bounds duplicates, never stored).
    const int lrow = (lane < 15) ? lane : 15;
    const int srow = wg * ROWS_PER_WG + lrow;

    // ---- per-row params/state (used only by wave 0)
    const float c_EL = p.E_L[srow],  c_Cm = p.C_m[srow], c_G   = p.G[srow];
    const float c_RI = p.R_I[srow],  c_fv = p.f_v[srow], c_fI  = p.f_I[srow];
    const float c_dts = p.dts[srow], c_bs = p.b_s[srow], c_av  = p.a_v[srow];
    const float c_bv  = p.b_v[srow], c_tinf = p.tinf[srow];
    const float c_dV  = p.dV[srow],  c_IA = p.I_A[srow];
    float v  = p.v0[srow], ts = p.ts0[srow], tv = p.tv0[srow];
    float ia_self = p.ia0[srow];

    // ---- w: 2 rows x 2048-col half-slice = 16 float4 registers
    const float4* w4 = (const float4*)p.w;           // [N][N/4]
    const size_t baseA = (size_t)(rowA    ) * (N/4) + (size_t)c * 512 + lane;
    const size_t baseB = (size_t)(rowA + 1) * (N/4) + (size_t)c * 512 + lane;
    const float4 a0 = w4[baseA+  0], a1 = w4[baseA+ 64], a2 = w4[baseA+128],
                 a3 = w4[baseA+192], a4 = w4[baseA+256], a5 = w4[baseA+320],
                 a6 = w4[baseA+384], a7 = w4[baseA+448];
    const float4 b0 = w4[baseB+  0], b1 = w4[baseB+ 64], b2 = w4[baseB+128],
                 b3 = w4[baseB+192], b4 = w4[baseB+256], b5 = w4[baseB+320],
                 b6 = w4[baseB+384], b7 = w4[baseB+448];

    // ---- init: zero own flag (kills 0xAA poison + stale replay tags);
    // stage LDS buffer 0 directly from ia0 (input; no cross-WG dependency)
    if (tid == 0) AGST(&p.flags[wg], 0u);
    ((float4*)ia_lds[0])[tid] = ((const float4*)p.ia0)[tid];
    grid.sync();                          // once per launch

    float x = p.x_in[srow];               // x for t=0 (wave0 lanes<16 meaningful)

    for (int t = 0; t < T; ++t) {
        const float4* lds4 =
            (const float4*)ia_lds[t & 1] + (size_t)c * 512 + lane;

        // ---- matvec: 2 rows x half-columns per wave, 8 b128 reads/lane
        float sA = 0.f, sB = 0.f;
        { float4 q = lds4[  0]; sA += DOT(a0,q); sB += DOT(b0,q); }
        { float4 q = lds4[ 64]; sA += DOT(a1,q); sB += DOT(b1,q); }
        { float4 q = lds4[128]; sA += DOT(a2,q); sB += DOT(b2,q); }
        { float4 q = lds4[192]; sA += DOT(a3,q); sB += DOT(b3,q); }
        { float4 q = lds4[256]; sA += DOT(a4,q); sB += DOT(b4,q); }
        { float4 q = lds4[320]; sA += DOT(a5,q); sB += DOT(b5,q); }
        { float4 q = lds4[384]; sA += DOT(a6,q); sB += DOT(b6,q); }
        { float4 q = lds4[448]; sA += DOT(a7,q); sB += DOT(b7,q); }

        #pragma unroll
        for (int m = 32; m >= 1; m >>= 1) {
            sA += __shfl_xor(sA, m, 64);
            sB += __shfl_xor(sB, m, 64);
        }

        // ---- deposit partials: part[row*2 + slice]; bank-conflict-free
        if (lane == 0) {
            part[(2*g + 0)*2 + c] = sA;
            part[(2*g + 1)*2 + c] = sB;
        }
        __syncthreads();                  // A: partials visible to wave 0

        const bool notlast = (t + 1 < T);
        float* dst = p.ia_buf + (size_t)((t + 1) & 1) * N;

        if (wave == 0) {
            // ---- final reduce: 2 partials per row
            float2 pr = *(const float2*)&part[2 * lrow];
            float a = pr.x + pr.y;

            // ---- neuron update (lanes >= 16 harmless duplicates)
            float I      = x + a;
            float dv     = (I * c_RI - c_G * (v - c_EL)) / c_Cm;
            float v_next = v + dv;
            float thr    = ts + tv;
            float ssoft  = 1.f / (1.f + __expf(thr - v_next));
            float ia_new = (1.f - c_fI) * ia_self + ssoft * c_IA;

            // ---- publish: ONE coalesced 64 B store, wave-local drain, flag
            if (lane < 16) AGST(&dst[srow], ia_new);
            asm volatile("s_waitcnt vmcnt(0)" ::: "memory");
            if (lane == 0 && notlast)
                AGST(&p.flags[wg], (unsigned)(t + 1));

            // ---- bookkeeping + out stores + x prefetch in the poll shadow
            bool  sp      = (v_next >= thr);
            float v_reset = c_EL + c_fv * (v - c_EL) - c_dV;
            float v_new   = sp ? v_reset : v_next;
            float ts_new  = (1.f - c_bs) * ts + (sp ? c_dts : 0.f);
            float dtv     = c_av * (v_new - c_EL) - c_bv * (tv - c_tinf);
            float tv_new  = tv + (sp ? 0.f : dtv);
            v = v_new; ts = ts_new; tv = tv_new; ia_self = ia_new;
            if (lane < 16) {
                p.out[(size_t)t * N + srow] = v_new;
                p.out[(size_t)T * N + (size_t)t * N + srow] = ssoft;
                if (notlast) x = p.x_in[(size_t)(t + 1) * N + srow];
            }

            // ---- poll all 256 flags (1 KB): 2 u64/lane, sticky >=
            if (notlast) {
                const unsigned tgt = (unsigned)(t + 1);
                const unsigned long long* f64 =
                    (const unsigned long long*)p.flags;
                bool d0 = false, d1 = false;
                for (;;) {
                    if (!d0) {
                        unsigned long long q = AGLD(&f64[lane]);
                        d0 = ((unsigned)q >= tgt) & ((unsigned)(q >> 32) >= tgt);
                    }
                    if (!d1) {
                        unsigned long long q = AGLD(&f64[lane + 64]);
                        d1 = ((unsigned)q >= tgt) & ((unsigned)(q >> 32) >= tgt);
                    }
                    if (__all(d0 && d1)) break;
                    __builtin_amdgcn_s_sleep(1);
                }
            }
        }
        __syncthreads();                  // B: all 256 WGs have published

        if (notlast) {
            // ---- bulk read fresh I_add (L3-direct): 16 B/thread, coalesced
            const unsigned long long* s64 = (const unsigned long long*)dst;
            unsigned long long qa = AGLD(&s64[2 * tid + 0]);
            unsigned long long qb = AGLD(&s64[2 * tid + 1]);
            unsigned long long* l64 = (unsigned long long*)ia_lds[(t + 1) & 1];
            l64[2 * tid + 0] = qa;
            l64[2 * tid + 1] = qb;
            __syncthreads();              // C: LDS buffer ready for next matvec
        }
    }
}

extern "C" void kernel_launch(void* const* d_in, const int* in_sizes, int n_in,
                              void* d_out, int out_size, void* d_ws, size_t ws_size,
                              hipStream_t stream)
{
    Params p;
    p.x_in = (const float*)d_in[0];
    p.w    = (const float*)d_in[1];
    p.E_L  = (const float*)d_in[2];
    p.C_m  = (const float*)d_in[3];
    p.G    = (const float*)d_in[4];
    p.R_I  = (const float*)d_in[5];
    p.f_v  = (const float*)d_in[6];
    p.f_I  = (const float*)d_in[7];
    p.dts  = (const float*)d_in[8];
    p.b_s  = (const float*)d_in[9];
    p.a_v  = (const float*)d_in[10];
    p.b_v  = (const float*)d_in[11];
    p.tinf = (const float*)d_in[12];
    p.dV   = (const float*)d_in[13];
    p.I_A  = (const float*)d_in[14];
    p.v0   = (const float*)d_in[15];
    p.ts0  = (const float*)d_in[16];
    p.tv0  = (const float*)d_in[17];
    p.ia0  = (const float*)d_in[18];
    p.out  = (float*)d_out;
    p.flags  = (unsigned*)d_ws;                      // 256 * 4 B = 1 KB
    p.ia_buf = (float*)((char*)d_ws + 4096);         // 2*N*4 = 32 KB

    void* args[] = { &p };
    hipLaunchCooperativeKernel((const void*)glif_persistent,
                               dim3(NBLK), dim3(NTHR), args, 0, stream);
}

// Round 11
// 7514.570 us; speedup vs baseline: 1.8204x; 1.4585x over previous
//
#include <hip/hip_runtime.h>
#include <hip/hip_cooperative_groups.h>

namespace cg = cooperative_groups;

constexpr int N    = 4096;
constexpr int T    = 2048;
constexpr int NBLK = 256;                 // one WG per CU
constexpr int NTHR = 1024;                // 16 waves
constexpr int ROWS_PER_WG = 16;

struct Params {
    const float *x_in, *w, *E_L, *C_m, *G, *R_I, *f_v, *f_I, *dts, *b_s,
                *a_v, *b_v, *tinf, *dV, *I_A, *v0, *ts0, *tv0, *ia0;
    float *out;          // [2, T, N]
    unsigned *flags;     // 256 u32 flags (1 KB) at d_ws
    float *ia_buf;       // double buffer 2*N floats at d_ws + 4 KB
};

#define DOT(wv, iv) ((wv).x*(iv).x + (wv).y*(iv).y + (wv).z*(iv).z + (wv).w*(iv).w)
#define AGLD(ptr) __hip_atomic_load(ptr, __ATOMIC_RELAXED, __HIP_MEMORY_SCOPE_AGENT)
#define AGST(ptr, val) __hip_atomic_store(ptr, val, __ATOMIC_RELAXED, __HIP_MEMORY_SCOPE_AGENT)

__global__ __launch_bounds__(NTHR, 1)
void glif_persistent(Params p)
{
    cg::grid_group grid = cg::this_grid();
    __shared__ float ia_lds[2][N];        // 32 KB double buffer
    __shared__ float part[2 * ROWS_PER_WG]; // part[2*r + c], 128 B

    const int tid  = threadIdx.x;
    const int wg   = blockIdx.x;
    const int wave = tid >> 6;
    const int lane = tid & 63;
    const int g    = wave >> 1;           // row-pair group 0..7
    const int c    = wave & 1;            // column half 0..1
    const int rowA = wg * ROWS_PER_WG + 2 * g;   // matvec rows: rowA, rowA+1

    // commit ownership: wave w owns row (wg*16 + w) — distributed like R5
    const int prow = wg * ROWS_PER_WG + wave;    // wave-uniform, in-bounds

    // ---- per-row params/state (wave-uniform -> scalarized)
    const float c_EL = p.E_L[prow],  c_Cm = p.C_m[prow], c_G   = p.G[prow];
    const float c_RI = p.R_I[prow],  c_fv = p.f_v[prow], c_fI  = p.f_I[prow];
    const float c_dts = p.dts[prow], c_bs = p.b_s[prow], c_av  = p.a_v[prow];
    const float c_bv  = p.b_v[prow], c_tinf = p.tinf[prow];
    const float c_dV  = p.dV[prow],  c_IA = p.I_A[prow];
    float v  = p.v0[prow], ts = p.ts0[prow], tv = p.tv0[prow];
    float ia_self = p.ia0[prow];          // this wave OWNS I_add[prow]

    // ---- w: 2 rows x 2048-col half-slice = 16 float4 registers
    const float4* w4 = (const float4*)p.w;           // [N][N/4]
    const size_t baseA = (size_t)(rowA    ) * (N/4) + (size_t)c * 512 + lane;
    const size_t baseB = (size_t)(rowA + 1) * (N/4) + (size_t)c * 512 + lane;
    const float4 a0 = w4[baseA+  0], a1 = w4[baseA+ 64], a2 = w4[baseA+128],
                 a3 = w4[baseA+192], a4 = w4[baseA+256], a5 = w4[baseA+320],
                 a6 = w4[baseA+384], a7 = w4[baseA+448];
    const float4 b0 = w4[baseB+  0], b1 = w4[baseB+ 64], b2 = w4[baseB+128],
                 b3 = w4[baseB+192], b4 = w4[baseB+256], b5 = w4[baseB+320],
                 b6 = w4[baseB+384], b7 = w4[baseB+448];

    // ---- init: zero own flag (kills 0xAA poison + stale replay tags);
    // stage LDS buffer 0 directly from ia0 (input; no cross-WG dependency)
    if (tid == 0) AGST(&p.flags[wg], 0u);
    ((float4*)ia_lds[0])[tid] = ((const float4*)p.ia0)[tid];
    grid.sync();                          // once per launch

    float x = p.x_in[prow];               // x for t=0 (wave-uniform)

    for (int t = 0; t < T; ++t) {
        const float4* lds4 =
            (const float4*)ia_lds[t & 1] + (size_t)c * 512 + lane;

        // ---- matvec: 2 rows x half-columns per wave, 8 b128 reads/lane
        float sA = 0.f, sB = 0.f;
        { float4 q = lds4[  0]; sA += DOT(a0,q); sB += DOT(b0,q); }
        { float4 q = lds4[ 64]; sA += DOT(a1,q); sB += DOT(b1,q); }
        { float4 q = lds4[128]; sA += DOT(a2,q); sB += DOT(b2,q); }
        { float4 q = lds4[192]; sA += DOT(a3,q); sB += DOT(b3,q); }
        { float4 q = lds4[256]; sA += DOT(a4,q); sB += DOT(b4,q); }
        { float4 q = lds4[320]; sA += DOT(a5,q); sB += DOT(b5,q); }
        { float4 q = lds4[384]; sA += DOT(a6,q); sB += DOT(b6,q); }
        { float4 q = lds4[448]; sA += DOT(a7,q); sB += DOT(b7,q); }

        #pragma unroll
        for (int m = 32; m >= 1; m >>= 1) {
            sA += __shfl_xor(sA, m, 64);
            sB += __shfl_xor(sB, m, 64);
        }

        // ---- pair exchange: part[2*r + c]
        if (lane == 0) {
            part[2 * (2*g + 0) + c] = sA;
            part[2 * (2*g + 1) + c] = sB;
        }
        __syncthreads();                  // A: partials visible to pair wave

        const bool notlast = (t + 1 < T);
        float* dst = p.ia_buf + (size_t)((t + 1) & 1) * N;

        // ---- DISTRIBUTED commit: wave w owns row w; all lanes redundant
        {
            float2 pr = *(const float2*)&part[2 * wave];  // broadcast read
            float a  = pr.x + pr.y;

            float I      = x + a;
            float dv     = (I * c_RI - c_G * (v - c_EL)) / c_Cm;
            float v_next = v + dv;
            float thr    = ts + tv;
            float ssoft  = 1.f / (1.f + __expf(thr - v_next));
            float ia_new = (1.f - c_fI) * ia_self + ssoft * c_IA;

            // publish I_add FIRST (16 waves in parallel, RTs overlap)
            if (lane == 0) AGST(&dst[prow], ia_new);

            __syncthreads();              // #1: vmcnt(0) -> all ia stores at L3

            if (wave == 0 && lane == 0 && notlast)
                AGST(&p.flags[wg], (unsigned)(t + 1));

            // ---- bookkeeping + out stores + x prefetch in the poll shadow
            bool  sp      = (v_next >= thr);
            float v_reset = c_EL + c_fv * (v - c_EL) - c_dV;
            float v_new   = sp ? v_reset : v_next;
            float ts_new  = (1.f - c_bs) * ts + (sp ? c_dts : 0.f);
            float dtv     = c_av * (v_new - c_EL) - c_bv * (tv - c_tinf);
            float tv_new  = tv + (sp ? 0.f : dtv);
            v = v_new; ts = ts_new; tv = tv_new; ia_self = ia_new;
            if (lane == 0) {
                p.out[(size_t)t * N + prow] = v_new;
                p.out[(size_t)T * N + (size_t)t * N + prow] = ssoft;
            }
            if (notlast) x = p.x_in[(size_t)(t + 1) * N + prow];
        }

        if (notlast) {
            if (wave == 0) {
                // ---- poll all 256 flags (1 KB): 2 u64/lane, sticky >=
                const unsigned tgt = (unsigned)(t + 1);
                const unsigned long long* f64 =
                    (const unsigned long long*)p.flags;
                bool d0 = false, d1 = false;
                for (;;) {
                    if (!d0) {
                        unsigned long long q = AGLD(&f64[lane]);
                        d0 = ((unsigned)q >= tgt) & ((unsigned)(q >> 32) >= tgt);
                    }
                    if (!d1) {
                        unsigned long long q = AGLD(&f64[lane + 64]);
                        d1 = ((unsigned)q >= tgt) & ((unsigned)(q >> 32) >= tgt);
                    }
                    if (__all(d0 && d1)) break;
                    __builtin_amdgcn_s_sleep(1);
                }
            }
            __syncthreads();              // #2: all 256 WGs have published

            // ---- bulk read fresh I_add (L3-direct): 16 B/thread, coalesced
            const unsigned long long* s64 = (const unsigned long long*)dst;
            unsigned long long qa = AGLD(&s64[2 * tid + 0]);
            unsigned long long qb = AGLD(&s64[2 * tid + 1]);
            unsigned long long* l64 = (unsigned long long*)ia_lds[(t + 1) & 1];
            l64[2 * tid + 0] = qa;
            l64[2 * tid + 1] = qb;
            __syncthreads();              // C: LDS buffer ready for next matvec
        }
    }
}

extern "C" void kernel_launch(void* const* d_in, const int* in_sizes, int n_in,
                              void* d_out, int out_size, void* d_ws, size_t ws_size,
                              hipStream_t stream)
{
    Params p;
    p.x_in = (const float*)d_in[0];
    p.w    = (const float*)d_in[1];
    p.E_L  = (const float*)d_in[2];
    p.C_m  = (const float*)d_in[3];
    p.G    = (const float*)d_in[4];
    p.R_I  = (const float*)d_in[5];
    p.f_v  = (const float*)d_in[6];
    p.f_I  = (const float*)d_in[7];
    p.dts  = (const float*)d_in[8];
    p.b_s  = (const float*)d_in[9];
    p.a_v  = (const float*)d_in[10];
    p.b_v  = (const float*)d_in[11];
    p.tinf = (const float*)d_in[12];
    p.dV   = (const float*)d_in[13];
    p.I_A  = (const float*)d_in[14];
    p.v0   = (const float*)d_in[15];
    p.ts0  = (const float*)d_in[16];
    p.tv0  = (const float*)d_in[17];
    p.ia0  = (const float*)d_in[18];
    p.out  = (float*)d_out;
    p.flags  = (unsigned*)d_ws;                      // 256 * 4 B = 1 KB
    p.ia_buf = (float*)((char*)d_ws + 4096);         // 2*N*4 = 32 KB

    void* args[] = { &p };
    hipLaunchCooperativeKernel((const void*)glif_persistent,
                               dim3(NBLK), dim3(NTHR), args, 0, stream);
}

// Round 12
// 7310.101 us; speedup vs baseline: 1.8713x; 1.0280x over previous
//
#include <hip/hip_runtime.h>
#include <hip/hip_cooperative_groups.h>

namespace cg = cooperative_groups;

constexpr int N    = 4096;
constexpr int T    = 2048;
constexpr int NBLK = 256;                 // one WG per CU
constexpr int NTHR = 1024;                // 16 waves
constexpr int ROWS_PER_WG = 16;

struct Params {
    const float *x_in, *w, *E_L, *C_m, *G, *R_I, *f_v, *f_I, *dts, *b_s,
                *a_v, *b_v, *tinf, *dV, *I_A, *v0, *ts0, *tv0, *ia0;
    float *out;          // [2, T, N]
    unsigned *flags;     // 256 u32 flags (1 KB) at d_ws
    float *ia_buf;       // double buffer 2*N floats at d_ws + 4 KB
};

#define DOT(wv, iv) ((wv).x*(iv).x + (wv).y*(iv).y + (wv).z*(iv).z + (wv).w*(iv).w)
#define AGLD(ptr) __hip_atomic_load(ptr, __ATOMIC_RELAXED, __HIP_MEMORY_SCOPE_AGENT)
#define AGST(ptr, val) __hip_atomic_store(ptr, val, __ATOMIC_RELAXED, __HIP_MEMORY_SCOPE_AGENT)
#define WGLD(ptr) __hip_atomic_load(ptr, __ATOMIC_RELAXED, __HIP_MEMORY_SCOPE_WORKGROUP)
#define WGST(ptr, val) __hip_atomic_store(ptr, val, __ATOMIC_RELAXED, __HIP_MEMORY_SCOPE_WORKGROUP)

__global__ __launch_bounds__(NTHR, 1)
void glif_persistent(Params p)
{
    cg::grid_group grid = cg::this_grid();
    __shared__ float ia_lds[N];                 // 16 KB, single buffer (R5)
    __shared__ unsigned long long mbox[8][2];   // pair-exchange mailboxes

    const int tid  = threadIdx.x;
    const int wg   = blockIdx.x;
    const int wave = tid >> 6;
    const int lane = tid & 63;
    const int g    = wave >> 1;           // row-pair group 0..7
    const int c    = wave & 1;            // column half 0..1
    const int rowA = wg * ROWS_PER_WG + 2 * g;   // matvec rows: rowA, rowA+1
    const int prow = rowA + c;            // commit row (wave-uniform)

    // ---- per-row params/state for the commit row (wave-uniform)
    const float c_EL = p.E_L[prow],  c_Cm = p.C_m[prow], c_G   = p.G[prow];
    const float c_RI = p.R_I[prow],  c_fv = p.f_v[prow], c_fI  = p.f_I[prow];
    const float c_dts = p.dts[prow], c_bs = p.b_s[prow], c_av  = p.a_v[prow];
    const float c_bv  = p.b_v[prow], c_tinf = p.tinf[prow];
    const float c_dV  = p.dV[prow],  c_IA = p.I_A[prow];
    float v  = p.v0[prow], ts = p.ts0[prow], tv = p.tv0[prow];
    float ia_self = p.ia0[prow];          // this wave OWNS I_add[prow]

    // ---- w: rows {rowA, rowA+1} x column-half c = 16 float4 registers
    const float4* w4 = (const float4*)p.w;           // [N][N/4]
    const size_t baseA = (size_t)(rowA    ) * (N/4) + (size_t)c * 512 + lane;
    const size_t baseB = (size_t)(rowA + 1) * (N/4) + (size_t)c * 512 + lane;
    const float4 a0 = w4[baseA+  0], a1 = w4[baseA+ 64], a2 = w4[baseA+128],
                 a3 = w4[baseA+192], a4 = w4[baseA+256], a5 = w4[baseA+320],
                 a6 = w4[baseA+384], a7 = w4[baseA+448];
    const float4 b0 = w4[baseB+  0], b1 = w4[baseB+ 64], b2 = w4[baseB+128],
                 b3 = w4[baseB+192], b4 = w4[baseB+256], b5 = w4[baseB+320],
                 b6 = w4[baseB+384], b7 = w4[baseB+448];

    // ---- init: zero own flag (kills 0xAA poison + stale replay tags),
    // zero mailboxes, publish ia_buf slot 0 from ia0 (threads 0..N-1 global)
    if (tid == 0) AGST(&p.flags[wg], 0u);
    if (tid < 16) mbox[tid >> 1][tid & 1] = 0ull;
    for (int i = wg * NTHR + tid; i < N; i += NBLK * NTHR)
        AGST(&p.ia_buf[i], p.ia0[i]);
    grid.sync();                          // once per launch

    float x = p.x_in[prow];               // x for t=0 (wave-uniform)

    for (int t = 0; t < T; ++t) {
        // ---- stage I_add into LDS via L3-direct loads (R5 pattern)
        {
            const unsigned long long* src64 =
                (const unsigned long long*)(p.ia_buf + (size_t)(t & 1) * N);
            unsigned long long q0 = AGLD(&src64[tid]);
            unsigned long long q1 = AGLD(&src64[tid + NTHR]);
            unsigned long long* l64 = (unsigned long long*)ia_lds;
            l64[tid]        = q0;
            l64[tid + NTHR] = q1;
        }
        __syncthreads();                  // T: LDS staged

        // ---- matvec: 2 rows x half-columns, 8 b128 reads/lane
        const float4* lds4 = (const float4*)ia_lds + (size_t)c * 512 + lane;
        float sA = 0.f, sB = 0.f;
        { float4 q = lds4[  0]; sA += DOT(a0,q); sB += DOT(b0,q); }
        { float4 q = lds4[ 64]; sA += DOT(a1,q); sB += DOT(b1,q); }
        { float4 q = lds4[128]; sA += DOT(a2,q); sB += DOT(b2,q); }
        { float4 q = lds4[192]; sA += DOT(a3,q); sB += DOT(b3,q); }
        { float4 q = lds4[256]; sA += DOT(a4,q); sB += DOT(b4,q); }
        { float4 q = lds4[320]; sA += DOT(a5,q); sB += DOT(b5,q); }
        { float4 q = lds4[384]; sA += DOT(a6,q); sB += DOT(b6,q); }
        { float4 q = lds4[448]; sA += DOT(a7,q); sB += DOT(b7,q); }

        #pragma unroll
        for (int m = 32; m >= 1; m >>= 1) {
            sA += __shfl_xor(sA, m, 64);
            sB += __shfl_xor(sB, m, 64);
        }

        // ---- barrier-free pair exchange via LDS mailbox.
        // I give my value for row index (1-c); partner gives me row index c.
        const unsigned tag = (unsigned)(t + 1);
        if (lane == 0) {
            float give = (c == 0) ? sB : sA;
            WGST(&mbox[g][c],
                 ((unsigned long long)tag << 32) |
                 (unsigned long long)__float_as_uint(give));
        }
        float apart;
        {
            unsigned long long q;
            do { q = WGLD(&mbox[g][1 - c]); } while ((unsigned)(q >> 32) != tag);
            apart = __uint_as_float((unsigned)q);
        }
        float a = ((c == 0) ? sA : sB) + apart;

        // ---- update front half: everything ia_new needs, then publish
        float I      = x + a;
        float dv     = (I * c_RI - c_G * (v - c_EL)) / c_Cm;
        float v_next = v + dv;
        float thr    = ts + tv;
        float ssoft  = 1.f / (1.f + __expf(thr - v_next)); // sigmoid(v_next-thr)
        float ia_new = (1.f - c_fI) * ia_self + ssoft * c_IA;

        float* dst = p.ia_buf + (size_t)((t + 1) & 1) * N;
        if (lane == 0) AGST(&dst[prow], ia_new);   // 16 waves publish in parallel

        __syncthreads();                  // #1: vmcnt(0) -> all ia stores at L3

        const bool notlast = (t + 1 < T);
        if (wave == 0 && lane == 0 && notlast)
            AGST(&p.flags[wg], tag);      // flag right after the drain barrier

        // ---- bookkeeping + out stores + x prefetch in the poll shadow
        {
            bool  sp      = (v_next >= thr);
            float v_reset = c_EL + c_fv * (v - c_EL) - c_dV;
            float v_new   = sp ? v_reset : v_next;
            float ts_new  = (1.f - c_bs) * ts + (sp ? c_dts : 0.f);
            float dtv     = c_av * (v_new - c_EL) - c_bv * (tv - c_tinf);
            float tv_new  = tv + (sp ? 0.f : dtv);
            v = v_new; ts = ts_new; tv = tv_new; ia_self = ia_new;
            if (lane == 0) {
                p.out[(size_t)t * N + prow] = v_new;
                p.out[(size_t)T * N + (size_t)t * N + prow] = ssoft;
            }
            if (notlast) x = p.x_in[(size_t)(t + 1) * N + prow];
        }

        if (notlast) {
            if (wave == 0) {
                // ---- poll all 256 packed flags (1 KB): 2 u64/lane, sticky >=
                const unsigned long long* f64 =
                    (const unsigned long long*)p.flags;
                bool d0 = false, d1 = false;
                for (;;) {
                    if (!d0) {
                        unsigned long long q = AGLD(&f64[lane]);
                        d0 = ((unsigned)q >= tag) & ((unsigned)(q >> 32) >= tag);
                    }
                    if (!d1) {
                        unsigned long long q = AGLD(&f64[lane + 64]);
                        d1 = ((unsigned)q >= tag) & ((unsigned)(q >> 32) >= tag);
                    }
                    if (__all(d0 && d1)) break;
                    __builtin_amdgcn_s_sleep(1);
                }
            }
            __syncthreads();              // #2: all 256 WGs have published
        }
    }
}

extern "C" void kernel_launch(void* const* d_in, const int* in_sizes, int n_in,
                              void* d_out, int out_size, void* d_ws, size_t ws_size,
                              hipStream_t stream)
{
    Params p;
    p.x_in = (const float*)d_in[0];
    p.w    = (const float*)d_in[1];
    p.E_L  = (const float*)d_in[2];
    p.C_m  = (const float*)d_in[3];
    p.G    = (const float*)d_in[4];
    p.R_I  = (const float*)d_in[5];
    p.f_v  = (const float*)d_in[6];
    p.f_I  = (const float*)d_in[7];
    p.dts  = (const float*)d_in[8];
    p.b_s  = (const float*)d_in[9];
    p.a_v  = (const float*)d_in[10];
    p.b_v  = (const float*)d_in[11];
    p.tinf = (const float*)d_in[12];
    p.dV   = (const float*)d_in[13];
    p.I_A  = (const float*)d_in[14];
    p.v0   = (const float*)d_in[15];
    p.ts0  = (const float*)d_in[16];
    p.tv0  = (const float*)d_in[17];
    p.ia0  = (const float*)d_in[18];
    p.out  = (float*)d_out;
    p.flags  = (unsigned*)d_ws;                      // 256 * 4 B = 1 KB
    p.ia_buf = (float*)((char*)d_ws + 4096);         // 2*N*4 = 32 KB

    void* args[] = { &p };
    hipLaunchCooperativeKernel((const void*)glif_persistent,
                               dim3(NBLK), dim3(NTHR), args, 0, stream);
}

// Round 14
// 6812.290 us; speedup vs baseline: 2.0081x; 1.0731x over previous
//
#include <hip/hip_runtime.h>
#include <hip/hip_cooperative_groups.h>

namespace cg = cooperative_groups;

constexpr int N    = 4096;
constexpr int T    = 2048;
constexpr int NBLK = 256;                 // one WG per CU
constexpr int NTHR = 1024;                // 16 waves
constexpr int ROWS_PER_WG = 16;           // 1 row per wave

struct Params {
    const float *x_in, *w, *E_L, *C_m, *G, *R_I, *f_v, *f_I, *dts, *b_s,
                *a_v, *b_v, *tinf, *dV, *I_A, *v0, *ts0, *tv0, *ia0;
    float *out;          // [2, T, N]
    unsigned *flags;     // 256 u32 flags (1 KB) at d_ws
    float *ia_buf;       // double buffer 2*N floats at d_ws + 4 KB
};

#define DOT(wv, iv) ((wv).x*(iv).x + (wv).y*(iv).y + (wv).z*(iv).z + (wv).w*(iv).w)
#define AGLD(ptr) __hip_atomic_load(ptr, __ATOMIC_RELAXED, __HIP_MEMORY_SCOPE_AGENT)
#define AGST(ptr, val) __hip_atomic_store(ptr, val, __ATOMIC_RELAXED, __HIP_MEMORY_SCOPE_AGENT)

// VALU-pipe cross-lane add via DPP (NOT the DS pipe, unlike __shfl_xor).
// CTRL must be an immediate -> template parameter.
// bound_ctrl=true -> out-of-range lanes contribute 0.0f (safe for sums).
template <int CTRL>
__device__ __forceinline__ float dpp_add(float x) {
    int sh = __builtin_amdgcn_update_dpp(0, __float_as_int(x), CTRL, 0xf, 0xf, true);
    return x + __int_as_float(sh);
}
// wave64 sum -> valid in lane 63; broadcast via readlane.
__device__ __forceinline__ float wave_sum_dpp(float x) {
    x = dpp_add<0x111>(x);   // row_shr:1
    x = dpp_add<0x112>(x);   // row_shr:2
    x = dpp_add<0x114>(x);   // row_shr:4
    x = dpp_add<0x118>(x);   // row_shr:8  -> lane15/31/47/63 = row sums
    x = dpp_add<0x142>(x);   // row_bcast:15 -> lane31 += r0 sum, lane63 += r2 sum
    x = dpp_add<0x143>(x);   // row_bcast:31 -> lane63 = total
    return __int_as_float(__builtin_amdgcn_readlane(__float_as_int(x), 63));
}

__global__ __launch_bounds__(NTHR, 1)
void glif_persistent(Params p)
{
    cg::grid_group grid = cg::this_grid();
    __shared__ float ia_lds[N];           // 16 KB, single buffer (R5)

    const int tid  = threadIdx.x;
    const int wg   = blockIdx.x;
    const int wave = tid >> 6;
    const int lane = tid & 63;
    const int row  = wg * ROWS_PER_WG + wave;   // wave-uniform neuron index

    // ---- wave-uniform params/state (scalarized by compiler)
    const float c_EL = p.E_L[row],  c_Cm = p.C_m[row], c_G   = p.G[row];
    const float c_RI = p.R_I[row],  c_fv = p.f_v[row], c_fI  = p.f_I[row];
    const float c_dts = p.dts[row], c_bs = p.b_s[row], c_av  = p.a_v[row];
    const float c_bv  = p.b_v[row], c_tinf = p.tinf[row];
    const float c_dV  = p.dV[row],  c_IA = p.I_A[row];
    float v  = p.v0[row], ts = p.ts0[row], tv = p.tv0[row];
    float ia = p.ia0[row];                // this wave OWNS I_add[row]

    // ---- this wave's w row in 16 named float4 regs (VGPR/AGPR resident)
    const float4* wr = (const float4*)(p.w + (size_t)row * N);
    const float4 w0  = wr[lane +   0], w1  = wr[lane +  64], w2  = wr[lane + 128],
                 w3  = wr[lane + 192], w4  = wr[lane + 256], w5  = wr[lane + 320],
                 w6  = wr[lane + 384], w7  = wr[lane + 448], w8  = wr[lane + 512],
                 w9  = wr[lane + 576], w10 = wr[lane + 640], w11 = wr[lane + 704],
                 w12 = wr[lane + 768], w13 = wr[lane + 832], w14 = wr[lane + 896],
                 w15 = wr[lane + 960];

    // ---- init: zero own flag (kills 0xAA poison + stale replay tags);
    // publish ia_buf slot 0 from ia0 (write-through so sc readers see it)
    if (tid == 0) AGST(&p.flags[wg], 0u);
    for (int i = wg * NTHR + tid; i < N; i += NBLK * NTHR)
        AGST(&p.ia_buf[i], p.ia0[i]);
    grid.sync();                          // once per launch

    const float4* lds4 = (const float4*)ia_lds;
    float x = p.x_in[row];                // x for t=0 (wave-uniform)

    for (int t = 0; t < T; ++t) {
        // ---- stage I_add into LDS via L3-direct loads (R5 pattern)
        {
            const unsigned long long* src64 =
                (const unsigned long long*)(p.ia_buf + (size_t)(t & 1) * N);
            unsigned long long q0 = AGLD(&src64[tid]);
            unsigned long long q1 = AGLD(&src64[tid + NTHR]);
            unsigned long long* l64 = (unsigned long long*)ia_lds;
            l64[tid]        = q0;
            l64[tid + NTHR] = q1;
        }
        __syncthreads();                  // T: LDS staged

        // ---- matvec from register-resident w (16 b128 reads/lane)
        float a = 0.f;
        { float4 q = lds4[lane +   0]; a += DOT(w0 , q); }
        { float4 q = lds4[lane +  64]; a += DOT(w1 , q); }
        { float4 q = lds4[lane + 128]; a += DOT(w2 , q); }
        { float4 q = lds4[lane + 192]; a += DOT(w3 , q); }
        { float4 q = lds4[lane + 256]; a += DOT(w4 , q); }
        { float4 q = lds4[lane + 320]; a += DOT(w5 , q); }
        { float4 q = lds4[lane + 384]; a += DOT(w6 , q); }
        { float4 q = lds4[lane + 448]; a += DOT(w7 , q); }
        { float4 q = lds4[lane + 512]; a += DOT(w8 , q); }
        { float4 q = lds4[lane + 576]; a += DOT(w9 , q); }
        { float4 q = lds4[lane + 640]; a += DOT(w10, q); }
        { float4 q = lds4[lane + 704]; a += DOT(w11, q); }
        { float4 q = lds4[lane + 768]; a += DOT(w12, q); }
        { float4 q = lds4[lane + 832]; a += DOT(w13, q); }
        { float4 q = lds4[lane + 896]; a += DOT(w14, q); }
        { float4 q = lds4[lane + 960]; a += DOT(w15, q); }

        // ---- VALU-pipe DPP reduction (frees the DS pipe, short dep chain)
        a = wave_sum_dpp(a);              // uniform across the wave

        // ---- front half of update: everything ia_new needs, then publish
        float I      = x + a;
        float dv     = (I * c_RI - c_G * (v - c_EL)) / c_Cm;
        float v_next = v + dv;
        float thr    = ts + tv;
        float ssoft  = 1.f / (1.f + __expf(thr - v_next)); // sigmoid(v_next-thr)
        float ia_new = (1.f - c_fI) * ia + ssoft * c_IA;

        float* dst = p.ia_buf + (size_t)((t + 1) & 1) * N;
        if (lane == 0) AGST(&dst[row], ia_new);  // 16 waves publish in parallel

        __syncthreads();                  // #1: vmcnt(0) -> all 16 ia stores at L3

        const bool notlast = (t + 1 < T);
        const unsigned tag = (unsigned)(t + 1);
        if (wave == 0 && lane == 0 && notlast)
            AGST(&p.flags[wg], tag);      // flag right after the drain barrier

        // ---- bookkeeping + out stores + x prefetch in the poll shadow
        {
            bool  sp      = (v_next >= thr);
            float v_reset = c_EL + c_fv * (v - c_EL) - c_dV;
            float v_new   = sp ? v_reset : v_next;
            float ts_new  = (1.f - c_bs) * ts + (sp ? c_dts : 0.f);
            float dtv     = c_av * (v_new - c_EL) - c_bv * (tv - c_tinf);
            float tv_new  = tv + (sp ? 0.f : dtv);
            v = v_new; ts = ts_new; tv = tv_new; ia = ia_new;
            if (lane == 0) {
                p.out[(size_t)t * N + row] = v_new;
                p.out[(size_t)T * N + (size_t)t * N + row] = ssoft;
            }
            if (notlast) x = p.x_in[(size_t)(t + 1) * N + row];
        }

        if (notlast) {
            if (wave == 0) {
                // ---- poll all 256 packed flags (1 KB): 2 u64/lane, sticky >=
                const unsigned long long* f64 =
                    (const unsigned long long*)p.flags;
                bool d0 = false, d1 = false;
                for (;;) {
                    if (!d0) {
                        unsigned long long q = AGLD(&f64[lane]);
                        d0 = ((unsigned)q >= tag) & ((unsigned)(q >> 32) >= tag);
                    }
                    if (!d1) {
                        unsigned long long q = AGLD(&f64[lane + 64]);
                        d1 = ((unsigned)q >= tag) & ((unsigned)(q >> 32) >= tag);
                    }
                    if (__all(d0 && d1)) break;
                    __builtin_amdgcn_s_sleep(1);
                }
            }
            __syncthreads();              // #2: all 256 WGs have published
        }
    }
}

extern "C" void kernel_launch(void* const* d_in, const int* in_sizes, int n_in,
                              void* d_out, int out_size, void* d_ws, size_t ws_size,
                              hipStream_t stream)
{
    Params p;
    p.x_in = (const float*)d_in[0];
    p.w    = (const float*)d_in[1];
    p.E_L  = (const float*)d_in[2];
    p.C_m  = (const float*)d_in[3];
    p.G    = (const float*)d_in[4];
    p.R_I  = (const float*)d_in[5];
    p.f_v  = (const float*)d_in[6];
    p.f_I  = (const float*)d_in[7];
    p.dts  = (const float*)d_in[8];
    p.b_s  = (const float*)d_in[9];
    p.a_v  = (const float*)d_in[10];
    p.b_v  = (const float*)d_in[11];
    p.tinf = (const float*)d_in[12];
    p.dV   = (const float*)d_in[13];
    p.I_A  = (const float*)d_in[14];
    p.v0   = (const float*)d_in[15];
    p.ts0  = (const float*)d_in[16];
    p.tv0  = (const float*)d_in[17];
    p.ia0  = (const float*)d_in[18];
    p.out  = (float*)d_out;
    p.flags  = (unsigned*)d_ws;                      // 256 * 4 B = 1 KB
    p.ia_buf = (float*)((char*)d_ws + 4096);         // 2*N*4 = 32 KB

    void* args[] = { &p };
    hipLaunchCooperativeKernel((const void*)glif_persistent,
                               dim3(NBLK), dim3(NTHR), args, 0, stream);
}